// Round 3
// baseline (594.060 us; speedup 1.0000x reference)
//
#include <hip/hip_runtime.h>
#include <hip/hip_bf16.h>
#include <stdint.h>

// Problem constants: T_OBS=8, T_PRE=12, B=524288, IN=2, E=16, H=8
#define T_OBS 8
#define T_PRE 12
#define BATCH 524288
#define H_DIM 8

__device__ __forceinline__ float fast_sigmoid(float x) {
    float e = __builtin_amdgcn_exp2f(-1.4426950408889634f * x);
    return __builtin_amdgcn_rcpf(1.0f + e);
}
__device__ __forceinline__ float fast_tanh(float x) {
    float e = __builtin_amdgcn_exp2f(2.8853900817779268f * x);
    return 1.0f - 2.0f * __builtin_amdgcn_rcpf(1.0f + e);
}

// ---------------------------------------------------------------------------
// Weight prep (f32 inputs): fold embedding into LSTM input weights.
// ws layout (floats), per LSTM (obs at +0, pre at +352):
//   [0..63]    Wx[32][2] = W_ih @ W_in        (gate-major rows: i,f,g,o x 8)
//   [64..319]  Wh[32][8] = W_hh
//   [320..351] Bb[32]    = W_ih @ b_in + b_ih + b_hh
// ---------------------------------------------------------------------------
__global__ void prep_weights(const float* __restrict__ W_in,
                             const float* __restrict__ b_in,
                             const float* __restrict__ W_ih_obs,
                             const float* __restrict__ W_hh_obs,
                             const float* __restrict__ b_ih_obs,
                             const float* __restrict__ b_hh_obs,
                             const float* __restrict__ W_ih_pre,
                             const float* __restrict__ W_hh_pre,
                             const float* __restrict__ b_ih_pre,
                             const float* __restrict__ b_hh_pre,
                             float* __restrict__ ws) {
    int t = threadIdx.x;            // 0..63; one wave
    int g = t & 31;
    bool pre = t >= 32;
    const float* W_ih = pre ? W_ih_pre : W_ih_obs;
    const float* W_hh = pre ? W_hh_pre : W_hh_obs;
    const float* b_ih = pre ? b_ih_pre : b_ih_obs;
    const float* b_hh = pre ? b_hh_pre : b_hh_obs;
    float* base = ws + (pre ? 352 : 0);

    float wx0 = 0.0f, wx1 = 0.0f;
    float bb = b_ih[g] + b_hh[g];
    #pragma unroll
    for (int e = 0; e < 16; e++) {
        float wie = W_ih[g * 16 + e];
        wx0 += wie * W_in[e * 2 + 0];
        wx1 += wie * W_in[e * 2 + 1];
        bb  += wie * b_in[e];
    }
    base[g * 2 + 0] = wx0;
    base[g * 2 + 1] = wx1;
    #pragma unroll
    for (int j = 0; j < 8; j++) base[64 + g * 8 + j] = W_hh[g * 8 + j];
    base[320 + g] = bb;
}

// ---------------------------------------------------------------------------
// Main kernel: one thread per batch element; wave-uniform weight reads.
// ---------------------------------------------------------------------------
__device__ __forceinline__ void lstm_step(float x0, float x1,
                                          const float* __restrict__ w,
                                          float h[H_DIM], float c[H_DIM]) {
    float hn[H_DIM];
    #pragma unroll
    for (int u = 0; u < H_DIM; u++) {
        float gi = w[320 + u]      + w[(u)      * 2] * x0 + w[(u)      * 2 + 1] * x1;
        float gf = w[320 + u + 8]  + w[(u + 8)  * 2] * x0 + w[(u + 8)  * 2 + 1] * x1;
        float gg = w[320 + u + 16] + w[(u + 16) * 2] * x0 + w[(u + 16) * 2 + 1] * x1;
        float go = w[320 + u + 24] + w[(u + 24) * 2] * x0 + w[(u + 24) * 2 + 1] * x1;
        #pragma unroll
        for (int j = 0; j < H_DIM; j++) {
            gi += w[64 + (u)      * 8 + j] * h[j];
            gf += w[64 + (u + 8)  * 8 + j] * h[j];
            gg += w[64 + (u + 16) * 8 + j] * h[j];
            go += w[64 + (u + 24) * 8 + j] * h[j];
        }
        float ci = fast_sigmoid(gi) * fast_tanh(gg);
        c[u] = fast_sigmoid(gf) * c[u] + ci;
        hn[u] = fast_sigmoid(go) * fast_tanh(c[u]);
    }
    #pragma unroll
    for (int u = 0; u < H_DIM; u++) h[u] = hn[u];
}

__global__ __launch_bounds__(256)
void lstm_encoder(const float2* __restrict__ obs,
                  const float2* __restrict__ pre,
                  const float4* __restrict__ h0,
                  const float4* __restrict__ c0,
                  const float4* __restrict__ c0p,
                  const float* __restrict__ w,
                  float* __restrict__ out) {
    int b = blockIdx.x * blockDim.x + threadIdx.x;

    float h[H_DIM], c[H_DIM];
    {
        float4 h01 = h0[(size_t)b * 2], h02 = h0[(size_t)b * 2 + 1];
        float4 c01 = c0[(size_t)b * 2], c02 = c0[(size_t)b * 2 + 1];
        h[0] = h01.x; h[1] = h01.y; h[2] = h01.z; h[3] = h01.w;
        h[4] = h02.x; h[5] = h02.y; h[6] = h02.z; h[7] = h02.w;
        c[0] = c01.x; c[1] = c01.y; c[2] = c01.z; c[3] = c01.w;
        c[4] = c02.x; c[5] = c02.y; c[6] = c02.z; c[7] = c02.w;
    }

    // --- obs phase: 8 steps ---
    for (int t = 0; t < T_OBS; t++) {
        float2 xv = obs[(size_t)t * BATCH + b];
        lstm_step(xv.x, xv.y, w, h, c);
    }

    // c_out flat layout (transpose-then-reshape): out[j*B + b] = h[b][j]
    #pragma unroll
    for (int j = 0; j < H_DIM; j++) out[(size_t)j * BATCH + b] = h[j];

    // --- pre phase: h carries over, c re-initialized from c0_pre ---
    {
        float4 c01 = c0p[(size_t)b * 2], c02 = c0p[(size_t)b * 2 + 1];
        c[0] = c01.x; c[1] = c01.y; c[2] = c01.z; c[3] = c01.w;
        c[4] = c02.x; c[5] = c02.y; c[6] = c02.z; c[7] = c02.w;
    }
    const float* w2 = w + 352;
    for (int t = 0; t < T_PRE; t++) {
        float2 xv = pre[(size_t)t * BATCH + b];
        lstm_step(xv.x, xv.y, w2, h, c);
    }

    #pragma unroll
    for (int j = 0; j < H_DIM; j++)
        out[(size_t)(H_DIM + j) * BATCH + b] = h[j];
}

extern "C" void kernel_launch(void* const* d_in, const int* in_sizes, int n_in,
                              void* d_out, int out_size, void* d_ws, size_t ws_size,
                              hipStream_t stream) {
    prep_weights<<<1, 64, 0, stream>>>(
        (const float*)d_in[5],  (const float*)d_in[6],
        (const float*)d_in[7],  (const float*)d_in[8],
        (const float*)d_in[9],  (const float*)d_in[10],
        (const float*)d_in[11], (const float*)d_in[12],
        (const float*)d_in[13], (const float*)d_in[14],
        (float*)d_ws);

    lstm_encoder<<<BATCH / 256, 256, 0, stream>>>(
        (const float2*)d_in[0], (const float2*)d_in[1],
        (const float4*)d_in[2], (const float4*)d_in[3], (const float4*)d_in[4],
        (const float*)d_ws, (float*)d_out);
}

// Round 4
// 364.963 us; speedup vs baseline: 1.6277x; 1.6277x over previous
//
#include <hip/hip_runtime.h>
#include <stdint.h>

// Problem constants: T_OBS=8, T_PRE=12, B=524288, IN=2, E=16, H=8
#define T_OBS 8
#define T_PRE 12
#define BATCH 524288
#define NWPH  192   // dwords per phase weight block in ws

typedef _Float16 f16x2 __attribute__((ext_vector_type(2)));

#define NLOG2E  (-1.4426950408889634f)   // -log2(e): sigmoid prescale
#define P2LOG2E ( 2.8853900817779268f)   // +2*log2(e): tanh prescale

// ---------------------------------------------------------------------------
// Weight prep: fold embedding into LSTM input weights, prescale gate rows by
// the exp2 argument factor, pack to f16 pairs for v_dot2_f32_f16.
// ws layout per phase (obs at +0, pre at +NWPH), in dwords:
//   [0..31]   bias f32, prescaled      (rows: i 0-7, f 8-15, g 16-23, o 24-31)
//   [32..63]  wx  f16x2 (w_x0,w_x1) per row, prescaled
//   [64..191] wh  f16x2 [row*4 + j] = (wh[2j],wh[2j+1]), prescaled
// ---------------------------------------------------------------------------
__global__ void prep_weights(const float* __restrict__ W_in,
                             const float* __restrict__ b_in,
                             const float* __restrict__ W_ih_obs,
                             const float* __restrict__ W_hh_obs,
                             const float* __restrict__ b_ih_obs,
                             const float* __restrict__ b_hh_obs,
                             const float* __restrict__ W_ih_pre,
                             const float* __restrict__ W_hh_pre,
                             const float* __restrict__ b_ih_pre,
                             const float* __restrict__ b_hh_pre,
                             float* __restrict__ ws) {
    int t = threadIdx.x;            // 0..63; one wave
    int g = t & 31;                 // row index
    bool pre = t >= 32;
    const float* W_ih = pre ? W_ih_pre : W_ih_obs;
    const float* W_hh = pre ? W_hh_pre : W_hh_obs;
    const float* b_ih = pre ? b_ih_pre : b_ih_obs;
    const float* b_hh = pre ? b_hh_pre : b_hh_obs;
    float* base = ws + (pre ? NWPH : 0);

    float scale = (g >= 16 && g < 24) ? P2LOG2E : NLOG2E;

    float wx0 = 0.f, wx1 = 0.f;
    float bb = b_ih[g] + b_hh[g];
    #pragma unroll
    for (int e = 0; e < 16; e++) {
        float wie = W_ih[g * 16 + e];
        wx0 += wie * W_in[e * 2 + 0];
        wx1 += wie * W_in[e * 2 + 1];
        bb  += wie * b_in[e];
    }
    base[g] = bb * scale;
    f16x2* wxp = (f16x2*)(base + 32);
    f16x2 vx; vx.x = (_Float16)(wx0 * scale); vx.y = (_Float16)(wx1 * scale);
    wxp[g] = vx;
    f16x2* whp = (f16x2*)(base + 64);
    #pragma unroll
    for (int j = 0; j < 4; j++) {
        f16x2 vh;
        vh.x = (_Float16)(W_hh[g * 8 + 2 * j    ] * scale);
        vh.y = (_Float16)(W_hh[g * 8 + 2 * j + 1] * scale);
        whp[g * 4 + j] = vh;
    }
}

// ---------------------------------------------------------------------------
// Main kernel: one thread per batch element. Weights register-resident.
// ---------------------------------------------------------------------------
__device__ __forceinline__ float sig_pre(float gp) {   // gp = -log2e * x
    float e = __builtin_amdgcn_exp2f(gp);
    return __builtin_amdgcn_rcpf(1.0f + e);
}

__device__ __forceinline__ void lstm_step(f16x2 xp,
                                          const float bias[32],
                                          const f16x2 wx[32],
                                          const f16x2 wh[128],
                                          f16x2 hp[4], float c[8]) {
    float hn[8];
    #pragma unroll
    for (int u = 0; u < 8; u++) {
        float gi = __builtin_amdgcn_fdot2(wx[u     ], xp, bias[u     ], false);
        float gf = __builtin_amdgcn_fdot2(wx[u +  8], xp, bias[u +  8], false);
        float gg = __builtin_amdgcn_fdot2(wx[u + 16], xp, bias[u + 16], false);
        float go = __builtin_amdgcn_fdot2(wx[u + 24], xp, bias[u + 24], false);
        #pragma unroll
        for (int j = 0; j < 4; j++) {
            gi = __builtin_amdgcn_fdot2(wh[(u     ) * 4 + j], hp[j], gi, false);
            gf = __builtin_amdgcn_fdot2(wh[(u +  8) * 4 + j], hp[j], gf, false);
            gg = __builtin_amdgcn_fdot2(wh[(u + 16) * 4 + j], hp[j], gg, false);
            go = __builtin_amdgcn_fdot2(wh[(u + 24) * 4 + j], hp[j], go, false);
        }
        float si = sig_pre(gi);
        float sf = sig_pre(gf);
        float so = sig_pre(go);
        float eg = __builtin_amdgcn_exp2f(gg);                     // prescaled +2log2e
        float tg = 1.0f - 2.0f * __builtin_amdgcn_rcpf(1.0f + eg); // tanh(g)
        float cn = sf * c[u] + si * tg;
        c[u] = cn;
        float ec = __builtin_amdgcn_exp2f(P2LOG2E * cn);
        float tc = 1.0f - 2.0f * __builtin_amdgcn_rcpf(1.0f + ec); // tanh(c)
        hn[u] = so * tc;
    }
    #pragma unroll
    for (int j = 0; j < 4; j++) {
        f16x2 v; v.x = (_Float16)hn[2 * j]; v.y = (_Float16)hn[2 * j + 1];
        hp[j] = v;
    }
}

__global__ __launch_bounds__(256, 2)
void lstm_encoder(const float2* __restrict__ obs,
                  const float2* __restrict__ pre,
                  const float4* __restrict__ h0,
                  const float4* __restrict__ c0,
                  const float4* __restrict__ c0p,
                  const float* __restrict__ w,
                  float* __restrict__ out) {
    int b = blockIdx.x * blockDim.x + threadIdx.x;

    f16x2 hp[4];
    float c[8];
    {
        float4 h01 = h0[(size_t)b * 2], h02 = h0[(size_t)b * 2 + 1];
        float4 c01 = c0[(size_t)b * 2], c02 = c0[(size_t)b * 2 + 1];
        hp[0].x = (_Float16)h01.x; hp[0].y = (_Float16)h01.y;
        hp[1].x = (_Float16)h01.z; hp[1].y = (_Float16)h01.w;
        hp[2].x = (_Float16)h02.x; hp[2].y = (_Float16)h02.y;
        hp[3].x = (_Float16)h02.z; hp[3].y = (_Float16)h02.w;
        c[0] = c01.x; c[1] = c01.y; c[2] = c01.z; c[3] = c01.w;
        c[4] = c02.x; c[5] = c02.y; c[6] = c02.z; c[7] = c02.w;
    }

    // --- load obs-phase weights into registers ---
    float bias[32]; f16x2 wx[32]; f16x2 wh[128];
    {
        const f16x2* wxs = (const f16x2*)(w + 32);
        const f16x2* whs = (const f16x2*)(w + 64);
        #pragma unroll
        for (int i = 0; i < 32; i++) { bias[i] = w[i]; wx[i] = wxs[i]; }
        #pragma unroll
        for (int i = 0; i < 128; i++) wh[i] = whs[i];
    }

    #pragma unroll 1
    for (int t = 0; t < T_OBS; t++) {
        float2 xv = obs[(size_t)t * BATCH + b];
        f16x2 xp; xp.x = (_Float16)xv.x; xp.y = (_Float16)xv.y;
        lstm_step(xp, bias, wx, wh, hp, c);
    }

    // c_out flat layout (transpose-then-reshape): out[j*B + b] = h[b][j]
    #pragma unroll
    for (int j = 0; j < 4; j++) {
        out[(size_t)(2 * j    ) * BATCH + b] = (float)hp[j].x;
        out[(size_t)(2 * j + 1) * BATCH + b] = (float)hp[j].y;
    }

    // --- pre phase: h carries over, c re-initialized, new weights ---
    {
        float4 c01 = c0p[(size_t)b * 2], c02 = c0p[(size_t)b * 2 + 1];
        c[0] = c01.x; c[1] = c01.y; c[2] = c01.z; c[3] = c01.w;
        c[4] = c02.x; c[5] = c02.y; c[6] = c02.z; c[7] = c02.w;
    }
    {
        const float* w2 = w + NWPH;
        const f16x2* wxs = (const f16x2*)(w2 + 32);
        const f16x2* whs = (const f16x2*)(w2 + 64);
        #pragma unroll
        for (int i = 0; i < 32; i++) { bias[i] = w2[i]; wx[i] = wxs[i]; }
        #pragma unroll
        for (int i = 0; i < 128; i++) wh[i] = whs[i];
    }

    #pragma unroll 1
    for (int t = 0; t < T_PRE; t++) {
        float2 xv = pre[(size_t)t * BATCH + b];
        f16x2 xp; xp.x = (_Float16)xv.x; xp.y = (_Float16)xv.y;
        lstm_step(xp, bias, wx, wh, hp, c);
    }

    #pragma unroll
    for (int j = 0; j < 4; j++) {
        out[(size_t)(8 + 2 * j    ) * BATCH + b] = (float)hp[j].x;
        out[(size_t)(8 + 2 * j + 1) * BATCH + b] = (float)hp[j].y;
    }
}

extern "C" void kernel_launch(void* const* d_in, const int* in_sizes, int n_in,
                              void* d_out, int out_size, void* d_ws, size_t ws_size,
                              hipStream_t stream) {
    prep_weights<<<1, 64, 0, stream>>>(
        (const float*)d_in[5],  (const float*)d_in[6],
        (const float*)d_in[7],  (const float*)d_in[8],
        (const float*)d_in[9],  (const float*)d_in[10],
        (const float*)d_in[11], (const float*)d_in[12],
        (const float*)d_in[13], (const float*)d_in[14],
        (float*)d_ws);

    lstm_encoder<<<BATCH / 256, 256, 0, stream>>>(
        (const float2*)d_in[0], (const float2*)d_in[1],
        (const float4*)d_in[2], (const float4*)d_in[3], (const float4*)d_in[4],
        (const float*)d_ws, (float*)d_out);
}